// Round 4
// baseline (274.171 us; speedup 1.0000x reference)
//
#include <hip/hip_runtime.h>
#include <stdint.h>

typedef unsigned short U16;
typedef unsigned int   U32;
typedef __attribute__((ext_vector_type(8))) short short8;   // 8 bf16 = 4 VGPRs (MFMA A/B frag)
typedef __attribute__((ext_vector_type(4))) float floatx4;  // MFMA C/D frag

#define HW 3136   // 56*56

__device__ __forceinline__ U16 f2b(float f){
    union { float f; unsigned int i; } v; v.f = f;
    unsigned int u = (v.i + 0x7FFFu + ((v.i >> 16) & 1u)) >> 16;  // RNE
    return (U16)u;
}
// load 8 consecutive fp32, round to bf16, return as MFMA 8x-bf16 fragment
__device__ __forceinline__ short8 pack8(const float* p){
    float4 a = *reinterpret_cast<const float4*>(p);
    float4 b = *reinterpret_cast<const float4*>(p + 4);
    short8 r;
    r[0]=(short)f2b(a.x); r[1]=(short)f2b(a.y); r[2]=(short)f2b(a.z); r[3]=(short)f2b(a.w);
    r[4]=(short)f2b(b.x); r[5]=(short)f2b(b.y); r[6]=(short)f2b(b.z); r[7]=(short)f2b(b.w);
    return r;
}

// ---------------------------------------------------------------------------
// k_pre: fold BN into fp32 scale/shift; transpose+convert w2 (fp32) ->
// bf16 [g][tap][oc 32][ic 32].
// bn layout (fp32): [0:128) s1 [128:256) sh1 [256:384) s2 [384:512) sh2
//                   [512:1024) s3 [1024:1536) sh3
// ---------------------------------------------------------------------------
__global__ void k_pre(const float* __restrict__ w2,
                      const float* g1, const float* b1, const float* m1, const float* v1,
                      const float* g2, const float* b2, const float* m2, const float* v2,
                      const float* g3, const float* b3, const float* m3, const float* v3,
                      U16* __restrict__ w2t, float* __restrict__ bn){
  int i = blockIdx.x * 256 + threadIdx.x;
  if (i < 4*9*32*32) {
    int ic  = i & 31;
    int oc  = (i >> 5) & 31;
    int gt  = i >> 10;          // g*9 + tap
    int g_  = gt / 9, tap = gt % 9;
    w2t[i] = f2b(w2[((g_*32 + oc)*32 + ic)*9 + tap]);
  } else {
    int j = i - 4*9*32*32;
    if (j >= 768) return;
    const float *gp, *bp, *mp, *vp; int c, so, sho;
    if (j < 128)      { c = j;       gp=g1; bp=b1; mp=m1; vp=v1; so = 0;   sho = 128;  }
    else if (j < 256) { c = j - 128; gp=g2; bp=b2; mp=m2; vp=v2; so = 256; sho = 384;  }
    else              { c = j - 256; gp=g3; bp=b3; mp=m3; vp=v3; so = 512; sho = 1024; }
    float s = gp[c] / sqrtf(vp[c] + 1e-5f);
    bn[so + c]  = s;
    bn[sho + c] = bp[c] - mp[c] * s;
  }
}

// ---------------------------------------------------------------------------
// k_conv1: t1 = mask * relu(bn1(conv1x1_g(mask * x)))   (512 -> 128, G=4)
// LDS-FREE: each wave owns 32 px x all 32 oc. B-frags gathered directly from
// x (8 coalesced dword lines per frag), no barriers. t1 written PX-MAJOR
// [px][32 oc] bf16 so downstream fragment loads are contiguous 16B.
// ---------------------------------------------------------------------------
__global__ __launch_bounds__(128) void k_conv1(const float* __restrict__ x,
        const float* __restrict__ mask, const float* __restrict__ w1,
        const float* __restrict__ bn, U16* __restrict__ t1){
  const int t = threadIdx.x;
  const int lane = t & 63, wave = t >> 6;
  const int quad = lane >> 4, l15 = lane & 15;
  const int b = blockIdx.z, g = blockIdx.y;
  const int px0 = blockIdx.x*64 + wave*32;
  const float* xg = x + (size_t)(b*512 + g*128)*HW;
  U16* t1g = t1 + (size_t)(b*4 + g)*HW*32;           // px-major group plane

  int pxl[2]; float mfr[2];
  #pragma unroll
  for (int pxt = 0; pxt < 2; ++pxt){
    int px = px0 + pxt*16 + l15;
    pxl[pxt] = px;
    int h = px / 56, w = px - h*56;
    mfr[pxt] = mask[((b*4 + g)*7 + (h>>3))*7 + (w>>3)];
  }
  // A fragments: w1 fp32 [oc(g*32..)][ic 128]
  const float* wg = w1 + (size_t)(g*32)*128;
  short8 afr[2][4];
  #pragma unroll
  for (int oct = 0; oct < 2; ++oct)
    #pragma unroll
    for (int ks = 0; ks < 4; ++ks)
      afr[oct][ks] = pack8(wg + (oct*16 + l15)*128 + ks*32 + quad*8);

  floatx4 acc[2][2] = {};
  #pragma unroll
  for (int ch = 0; ch < 4; ++ch){
    #pragma unroll
    for (int pxt = 0; pxt < 2; ++pxt){
      const float* bp = xg + (size_t)(ch*32 + quad*8)*HW + pxl[pxt];
      float m = mfr[pxt];
      short8 bfr;
      #pragma unroll
      for (int j = 0; j < 8; ++j)
        bfr[j] = (short)f2b(bp[(size_t)j*HW] * m);   // 8 coalesced dword lines
      acc[0][pxt] = __builtin_amdgcn_mfma_f32_16x16x32_bf16(afr[0][ch], bfr, acc[0][pxt], 0,0,0);
      acc[1][pxt] = __builtin_amdgcn_mfma_f32_16x16x32_bf16(afr[1][ch], bfr, acc[1][pxt], 0,0,0);
    }
  }
  #pragma unroll
  for (int oct = 0; oct < 2; ++oct){
    const float* scp = bn + g*32 + oct*16 + quad*4;
    const float* shp = scp + 128;
    #pragma unroll
    for (int pxt = 0; pxt < 2; ++pxt){
      float m = mfr[pxt];
      U16 y[4];
      #pragma unroll
      for (int reg = 0; reg < 4; ++reg)
        y[reg] = f2b(fmaxf(scp[reg]*acc[oct][pxt][reg] + shp[reg], 0.0f) * m);
      uint2 pk = make_uint2((U32)y[0] | ((U32)y[1]<<16), (U32)y[2] | ((U32)y[3]<<16));
      *reinterpret_cast<uint2*>(t1g + (size_t)pxl[pxt]*32 + oct*16 + quad*4) = pk;
    }
  }
}

// ---------------------------------------------------------------------------
// k_conv2: t2 = mask * relu(bn2(conv3x3_g(t1)))   (128 -> 128, G=4, pad 1)
// LDS-FREE: t1 is px-major, so each tap's B-frag is ONE contiguous 16B load
// (L3-resident, 9x tap reuse served by cache). Halo = per-lane bounds check
// -> zero. Output written px-major (exact zeros in masked cells).
// ---------------------------------------------------------------------------
__global__ __launch_bounds__(256) void k_conv2(const U16* __restrict__ t1,
        const float* __restrict__ mask, const U16* __restrict__ w2t,
        const float* __restrict__ bn, U16* __restrict__ t2){
  const int t = threadIdx.x;
  const int lane = t & 63, wave = t >> 6;
  const int quad = lane >> 4, l15 = lane & 15;
  const int oct = wave & 1;
  const int b = blockIdx.z, g = blockIdx.y;
  const int px0 = blockIdx.x*64 + (wave>>1)*32;
  const U16* tg = t1 + (size_t)(b*4 + g)*HW*32;
  U16*       og = t2 + (size_t)(b*4 + g)*HW*32;

  int pxl[2], hh[2], wwc[2]; float mfr[2];
  #pragma unroll
  for (int pxt = 0; pxt < 2; ++pxt){
    int px = px0 + pxt*16 + l15;
    pxl[pxt] = px;
    int h = px / 56, w = px - h*56;
    hh[pxt] = h; wwc[pxt] = w;
    mfr[pxt] = mask[((b*4 + g)*7 + (h>>3))*7 + (w>>3)];
  }
  const U16* wg = w2t + g*9*32*32;                   // bf16 [tap][oc][ic]
  floatx4 acc[2] = {};
  #pragma unroll
  for (int kh = 0; kh < 3; ++kh)
    #pragma unroll
    for (int kw = 0; kw < 3; ++kw){
      int tap = kh*3 + kw;
      short8 a = *reinterpret_cast<const short8*>(wg + (tap*32 + oct*16 + l15)*32 + quad*8);
      #pragma unroll
      for (int pxt = 0; pxt < 2; ++pxt){
        int r = hh[pxt] + kh - 1, c = wwc[pxt] + kw - 1;
        short8 bfr;
        #pragma unroll
        for (int j = 0; j < 8; ++j) bfr[j] = 0;
        if ((unsigned)r < 56u && (unsigned)c < 56u)
          bfr = *reinterpret_cast<const short8*>(tg + (size_t)(r*56 + c)*32 + quad*8);
        acc[pxt] = __builtin_amdgcn_mfma_f32_16x16x32_bf16(a, bfr, acc[pxt], 0,0,0);
      }
    }
  const float* scp = bn + 256 + g*32 + oct*16 + quad*4;
  const float* shp = bn + 384 + g*32 + oct*16 + quad*4;
  #pragma unroll
  for (int pxt = 0; pxt < 2; ++pxt){
    float m = mfr[pxt];
    U16 y[4];
    #pragma unroll
    for (int reg = 0; reg < 4; ++reg)
      y[reg] = f2b(fmaxf(scp[reg]*acc[pxt][reg] + shp[reg], 0.0f) * m);
    uint2 pk = make_uint2((U32)y[0] | ((U32)y[1]<<16), (U32)y[2] | ((U32)y[3]<<16));
    *reinterpret_cast<uint2*>(og + (size_t)pxl[pxt]*32 + oct*16 + quad*4) = pk;
  }
}

// ---------------------------------------------------------------------------
// k_conv3: out = relu(bn3(conv1x1_g(t2)) + x)   (128 -> 512, G=4), fp32 out.
// LDS-FREE: B-frags = one contiguous 16B load from px-major t2. Each wave:
// 32 px x 4 octs (oct-half split across waves). Residual dword ops coalesce
// in full 64B lines.
// ---------------------------------------------------------------------------
__global__ __launch_bounds__(256) void k_conv3(const U16* __restrict__ t2,
        const float* __restrict__ x, const float* __restrict__ w3,
        const float* __restrict__ bn, float* __restrict__ out){
  const int t = threadIdx.x;
  const int lane = t & 63, wave = t >> 6;
  const int quad = lane >> 4, l15 = lane & 15;
  const int oh = wave & 1;                           // oct half: 0..3 / 4..7
  const int b = blockIdx.z, g = blockIdx.y;
  const int px0 = blockIdx.x*64 + (wave>>1)*32;
  const U16* tg = t2 + (size_t)(b*4 + g)*HW*32;
  const float* xg = x + (size_t)(b*512 + g*128)*HW;
  float*       og = out + (size_t)(b*512 + g*128)*HW;

  int pxl[2];
  short8 bfr[2];
  #pragma unroll
  for (int pxt = 0; pxt < 2; ++pxt){
    int px = px0 + pxt*16 + l15;
    pxl[pxt] = px;
    bfr[pxt] = *reinterpret_cast<const short8*>(tg + (size_t)px*32 + quad*8);
  }
  #pragma unroll
  for (int o4 = 0; o4 < 4; ++o4){
    int oct = oh*4 + o4;
    short8 afr = pack8(w3 + (size_t)(g*128 + oct*16 + l15)*32 + quad*8);  // fp32 [oc][ic32]
    floatx4 acc[2] = {};
    #pragma unroll
    for (int pxt = 0; pxt < 2; ++pxt)
      acc[pxt] = __builtin_amdgcn_mfma_f32_16x16x32_bf16(afr, bfr[pxt], acc[pxt], 0,0,0);
    const float* scp = bn + 512 + g*128 + oct*16 + quad*4;
    const float* shp = bn + 1024 + g*128 + oct*16 + quad*4;
    #pragma unroll
    for (int reg = 0; reg < 4; ++reg){
      int oc = oct*16 + quad*4 + reg;
      float sc = scp[reg], sh = shp[reg];
      #pragma unroll
      for (int pxt = 0; pxt < 2; ++pxt){
        size_t o2 = (size_t)oc*HW + pxl[pxt];
        og[o2] = fmaxf(sc*acc[pxt][reg] + sh + xg[o2], 0.0f);
      }
    }
  }
}

// ---------------------------------------------------------------------------
extern "C" void kernel_launch(void* const* d_in, const int* in_sizes, int n_in,
                              void* d_out, int out_size, void* d_ws, size_t ws_size,
                              hipStream_t stream){
  const float* x    = (const float*)d_in[0];
  const float* mask = (const float*)d_in[1];
  const float* w1   = (const float*)d_in[2];
  const float* g1   = (const float*)d_in[3];
  const float* b1   = (const float*)d_in[4];
  const float* m1   = (const float*)d_in[5];
  const float* v1   = (const float*)d_in[6];
  const float* w2   = (const float*)d_in[7];
  const float* g2   = (const float*)d_in[8];
  const float* b2   = (const float*)d_in[9];
  const float* m2   = (const float*)d_in[10];
  const float* v2   = (const float*)d_in[11];
  const float* w3   = (const float*)d_in[12];
  const float* g3   = (const float*)d_in[13];
  const float* b3   = (const float*)d_in[14];
  const float* m3   = (const float*)d_in[15];
  const float* v3   = (const float*)d_in[16];

  char* ws = (char*)d_ws;
  U16*   w2t = (U16*)ws;                               //      0 .. 73,728
  float* bn  = (float*)(ws + 73728);                   // 73,728 .. 79,872
  U16*   t1  = (U16*)(ws + 79872);                     // 12,845,056 B (px-major)
  U16*   t2  = (U16*)(ws + 79872 + 12845056);          // 12,845,056 B (px-major)

  k_pre<<<147, 256, 0, stream>>>(w2, g1,b1,m1,v1, g2,b2,m2,v2, g3,b3,m3,v3, w2t, bn);
  dim3 grid(49, 4, 16);   // (px-block of 64, group, batch)
  k_conv1<<<grid, 128, 0, stream>>>(x, mask, w1, bn, t1);
  k_conv2<<<grid, 256, 0, stream>>>(t1, mask, w2t, bn, t2);
  k_conv3<<<grid, 256, 0, stream>>>(t2, x, w3, bn, (float*)d_out);
}